// Round 6
// baseline (251.848 us; speedup 1.0000x reference)
//
#include <hip/hip_runtime.h>
#include <math.h>

#define BDIM 64
#define NN   2048
#define EE   8192
#define LL   50
#define DD   128
#define RR   5
#define NBASES 4
#define H3   192
#define RECCAP 1024
#define KDIM 768          // 128 (root) + 5*128 (relations)
#define GROWS 8           // rows per gemm block (one per wave, 512 threads)

// ---------------------------------------------------------------------------
// K1: all small precomputes in one launch.
//   blocks [0,384):   Wcat[768][128] = [root_w ; W_r = comp.bases]
//   blocks [384,512): A[i][j] = wq[i]·wk[j]
//   block  512:       va/vf = wv·attn_w / wv·fc_w
// ---------------------------------------------------------------------------
__global__ __launch_bounds__(256) void precompute_all(
        const float* __restrict__ bases, const float* __restrict__ comp,
        const float* __restrict__ root_w, const float* __restrict__ wq,
        const float* __restrict__ wk, const float* __restrict__ wv,
        const float* __restrict__ attn_w, const float* __restrict__ fc_w,
        float* __restrict__ Wcat, float* __restrict__ A,
        float* __restrict__ va, float* __restrict__ vf) {
    int blk = blockIdx.x, t = threadIdx.x;
    if (blk < 384) {
        int idx = blk * 256 + t;              // < 98304 = 768*128
        int k = idx >> 7, o = idx & 127;
        if (k < DD) {
            Wcat[idx] = root_w[idx];
        } else {
            int r = (k - DD) >> 7, i = (k - DD) & 127;
            float s = 0.f;
#pragma unroll
            for (int bb = 0; bb < NBASES; ++bb)
                s += comp[r * NBASES + bb] * bases[bb * DD * DD + i * DD + o];
            Wcat[idx] = s;
        }
    } else if (blk < 512) {
        int i = blk - 384;
        __shared__ float wqs[H3];
        if (t < H3) wqs[t] = wq[i * H3 + t];
        __syncthreads();
        if (t < DD) {
            const float4* wkr = (const float4*)(wk + t * H3);
            float s = 0.f;
#pragma unroll
            for (int d4 = 0; d4 < H3 / 4; ++d4) {
                float4 v = wkr[d4];
                s += wqs[4*d4]*v.x + wqs[4*d4+1]*v.y + wqs[4*d4+2]*v.z + wqs[4*d4+3]*v.w;
            }
            A[i * DD + t] = s;
        }
    } else {
        if (t < DD) {
            const float4* wr = (const float4*)(wv + t * H3);
            float a = 0.f, f = 0.f;
#pragma unroll
            for (int d4 = 0; d4 < H3 / 4; ++d4) {
                float4 v = wr[d4];
                a += v.x*attn_w[4*d4] + v.y*attn_w[4*d4+1] + v.z*attn_w[4*d4+2] + v.w*attn_w[4*d4+3];
                f += v.x*fc_w[4*d4] + v.y*fc_w[4*d4+1] + v.z*fc_w[4*d4+2] + v.w*fc_w[4*d4+3];
            }
            va[t] = a; vf[t] = f;
        }
    }
}

// ---------------------------------------------------------------------------
// K2: matchseg — one block per batch. Scan edges once, bucket matches by
// (l,r) with an LDS prefix sum -> segmented recbuf2 + segoff[b][251].
// ---------------------------------------------------------------------------
__global__ __launch_bounds__(512) void matchseg(const int* __restrict__ edge_index,
                                                const int* __restrict__ edge_type,
                                                const int* __restrict__ sent_ids,
                                                int* __restrict__ rep,
                                                int* __restrict__ segoff,
                                                int* __restrict__ recbuf2) {
    int b = blockIdx.x, t = threadIdx.x;
    __shared__ int mark[NN];
    __shared__ int scnt[LL * RR];
    __shared__ int soff[LL * RR + 1];
    __shared__ int scan[256];
    __shared__ int recs[RECCAP];
    __shared__ int lcnt;

    for (int i = t; i < NN; i += 512) mark[i] = -1;
    if (t < LL * RR) scnt[t] = 0;
    if (t == 0) lcnt = 0;
    __syncthreads();
    const int* sb = sent_ids + b * LL;
    if (t < LL) mark[sb[t]] = t;            // duplicates: arbitrary but consistent winner
    __syncthreads();
    if (t < LL) rep[b * LL + t] = mark[sb[t]];

    const int* src_arr = edge_index + (size_t)b * 2 * EE;
    const int* tgt_arr = src_arr + EE;
    const int* et_arr  = edge_type + (size_t)b * EE;
    const int4* tgt4 = (const int4*)tgt_arr;
    for (int i4 = t; i4 < EE / 4; i4 += 512) {
        int4 v = tgt4[i4];
        int e0 = 4 * i4;
        int lv[4] = {mark[v.x], mark[v.y], mark[v.z], mark[v.w]};
#pragma unroll
        for (int k = 0; k < 4; ++k) {
            int l = lv[k];
            if (l >= 0) {
                int e = e0 + k;
                int r = et_arr[e];
                int s = src_arr[e];
                int pos = atomicAdd(&lcnt, 1);
                if (pos < RECCAP) {
                    recs[pos] = (l << 14) | (r << 11) | s;
                    atomicAdd(&scnt[l * RR + r], 1);
                }
            }
        }
    }
    __syncthreads();
    // inclusive scan of scnt[0..249] over 256 lanes (Hillis-Steele)
    if (t < 256) scan[t] = (t < LL * RR) ? scnt[t] : 0;
    __syncthreads();
    for (int off = 1; off < 256; off <<= 1) {
        int v = 0;
        if (t < 256 && t >= off) v = scan[t - off];
        __syncthreads();
        if (t < 256) scan[t] += v;
        __syncthreads();
    }
    if (t == 0) soff[0] = 0;
    if (t < LL * RR) soff[t + 1] = scan[t];
    if (t < LL * RR) scnt[t] = 0;           // reset cursors
    __syncthreads();
    if (t <= LL * RR) segoff[b * (LL * RR + 1) + t] = soff[t];
    int nm = (lcnt < RECCAP) ? lcnt : RECCAP;
    for (int i = t; i < nm; i += 512) {
        int rc = recs[i];
        int key = (rc >> 14) * RR + ((rc >> 11) & 7);
        int pos = soff[key] + atomicAdd(&scnt[key], 1);
        recbuf2[b * RECCAP + pos] = rc;
    }
}

// ---------------------------------------------------------------------------
// K3: gemm_fused — 8 rows/block, 512 threads (wave w owns row w).
// Phase A (per wave): gather xnode + per-relation mean sums into Us[w].
// Phase B: X[row] = Us[w] @ Wcat + root_b (lane owns 2 cols, K in own Us row).
// Phase C: XA[row] = X[row] @ A ; p = X·va, q = X·vf (from registers).
// Only one barrier (for vas/vfs staging) — no cross-wave LDS sharing.
// ---------------------------------------------------------------------------
__global__ __launch_bounds__(512) void gemm_fused(const float* __restrict__ emb,
                                                  const float* __restrict__ Wcat,
                                                  const float* __restrict__ A,
                                                  const float* __restrict__ root_b,
                                                  const float* __restrict__ va,
                                                  const float* __restrict__ vf,
                                                  const int* __restrict__ node_ids,
                                                  const int* __restrict__ sent_ids,
                                                  const int* __restrict__ rep,
                                                  const int* __restrict__ segoff,
                                                  const int* __restrict__ recbuf2,
                                                  float* __restrict__ Xws,
                                                  float* __restrict__ XAws,
                                                  float* __restrict__ pv,
                                                  float* __restrict__ qv) {
    __shared__ float Us[GROWS][KDIM];      // 24 KB
    __shared__ float Xs[GROWS][DD];        // 4 KB
    __shared__ float vas[DD], vfs[DD];

    int t = threadIdx.x;
    int w = t >> 6, lane = t & 63;
    int row0 = blockIdx.x * GROWS;
    int bl = row0 + w;
    int b  = bl / LL;
    const int* nid = node_ids + (size_t)b * NN;

    // --- Phase A: gather into Us[w] (per-wave, lane covers dims lane, lane+64)
    {
        int myrep = rep[bl];
        const int* so = segoff + b * (LL * RR + 1) + myrep * RR;
        const int* rb = recbuf2 + b * RECCAP;
        int nrow = nid[sent_ids[bl]];
        Us[w][lane]      = emb[(size_t)nrow * DD + lane];
        Us[w][lane + 64] = emb[(size_t)nrow * DD + 64 + lane];
#pragma unroll
        for (int r = 0; r < RR; ++r) {
            int s0 = so[r], s1 = so[r + 1];
            float a0 = 0.f, a1 = 0.f;
            for (int j = s0; j < s1; ++j) {
                int s = rb[j] & 2047;
                int rw = nid[s];
                a0 += emb[(size_t)rw * DD + lane];
                a1 += emb[(size_t)rw * DD + 64 + lane];
            }
            float inv = (s1 > s0) ? 1.f / (float)(s1 - s0) : 0.f;
            Us[w][DD + r * DD + lane]      = a0 * inv;
            Us[w][DD + r * DD + 64 + lane] = a1 * inv;
        }
    }
    if (t < DD) { vas[t] = va[t]; vfs[t] = vf[t]; }
    __syncthreads();

    // --- Phase B: X row
    int tc = lane;                          // col-pair index, cols 2tc, 2tc+1
    float2 acc = *(const float2*)(root_b + 2 * tc);
    const float2* W2 = (const float2*)Wcat;
    const float4* u4 = (const float4*)Us[w];
#pragma unroll 2
    for (int k4 = 0; k4 < KDIM / 4; ++k4) {
        float4 u = u4[k4];
        int k = 4 * k4;
        float2 w0 = W2[(k + 0) * 64 + tc];
        float2 w1 = W2[(k + 1) * 64 + tc];
        float2 w2 = W2[(k + 2) * 64 + tc];
        float2 w3 = W2[(k + 3) * 64 + tc];
        acc.x = fmaf(u.x, w0.x, acc.x); acc.y = fmaf(u.x, w0.y, acc.y);
        acc.x = fmaf(u.y, w1.x, acc.x); acc.y = fmaf(u.y, w1.y, acc.y);
        acc.x = fmaf(u.z, w2.x, acc.x); acc.y = fmaf(u.z, w2.y, acc.y);
        acc.x = fmaf(u.w, w3.x, acc.x); acc.y = fmaf(u.w, w3.y, acc.y);
    }
    *(float2*)&Xs[w][2 * tc] = acc;
    *(float2*)(Xws + (size_t)bl * DD + 2 * tc) = acc;
    // same-wave LDS write->read ordering is guaranteed (in-order DS ops)

    // --- Phase C: XA row
    float2 z = {0.f, 0.f};
    const float2* A2 = (const float2*)A;
    const float4* x4 = (const float4*)Xs[w];
#pragma unroll 2
    for (int k4 = 0; k4 < DD / 4; ++k4) {
        float4 x = x4[k4];
        int k = 4 * k4;
        float2 a0 = A2[(k + 0) * 64 + tc];
        float2 a1 = A2[(k + 1) * 64 + tc];
        float2 a2 = A2[(k + 2) * 64 + tc];
        float2 a3 = A2[(k + 3) * 64 + tc];
        z.x = fmaf(x.x, a0.x, z.x); z.y = fmaf(x.x, a0.y, z.y);
        z.x = fmaf(x.y, a1.x, z.x); z.y = fmaf(x.y, a1.y, z.y);
        z.x = fmaf(x.z, a2.x, z.x); z.y = fmaf(x.z, a2.y, z.y);
        z.x = fmaf(x.w, a3.x, z.x); z.y = fmaf(x.w, a3.y, z.y);
    }
    *(float2*)(XAws + (size_t)bl * DD + 2 * tc) = z;

    // --- p/q from this thread's X cols (registers)
    float pp = acc.x * vas[2 * tc] + acc.y * vas[2 * tc + 1];
    float qq = acc.x * vfs[2 * tc] + acc.y * vfs[2 * tc + 1];
#pragma unroll
    for (int off = 32; off; off >>= 1) {
        pp += __shfl_xor(pp, off);
        qq += __shfl_xor(qq, off);
    }
    if (lane == 0) { pv[bl] = pp; qv[bl] = qq; }
}

// ---------------------------------------------------------------------------
// K4: attn_batch — one block (4 waves) per batch. X staged transposed as
// float4 (XT4[k][m]), lane m owns score column m. Wave w handles rows
// l = w, w+4, ... Softmax + pooled product in-wave; out[b] written directly.
// ---------------------------------------------------------------------------
__global__ __launch_bounds__(256) void attn_batch(const float* __restrict__ Xws,
                                                  const float* __restrict__ XAws,
                                                  const float* __restrict__ pv,
                                                  const float* __restrict__ qv,
                                                  const float* __restrict__ attn_b,
                                                  const float* __restrict__ fc_b,
                                                  float* __restrict__ out) {
    __shared__ float4 XT4[32][64];    // XT4[k][m] = X[m][4k..4k+3]; 32 KB
    __shared__ float4 XA4[LL][32];    // XA rows as float4; 25.6 KB
    __shared__ float pvs[64], qvs[64];
    __shared__ float partial[4];

    int b = blockIdx.x, t = threadIdx.x;
    int w = t >> 6, lane = t & 63;

    const float4* Xb4  = (const float4*)(Xws  + (size_t)b * LL * DD);
    const float4* XAb4 = (const float4*)(XAws + (size_t)b * LL * DD);
    for (int idx = t; idx < LL * 32; idx += 256) {
        int m = idx >> 5, k = idx & 31;
        XT4[k][m] = Xb4[idx];                 // coalesced read, scattered LDS write
        ((float4*)XA4)[idx] = XAb4[idx];
    }
    if (t < 64) {
        pvs[t] = (t < LL) ? pv[b * LL + t] : 0.f;
        qvs[t] = (t < LL) ? qv[b * LL + t] : 0.f;
    }
    __syncthreads();

    const float scale = 0.07216878364870322f;  // 1/sqrt(192)
    float ab = attn_b[0];
    float local = 0.f;
    for (int l = w; l < LL; l += 4) {
        float s = 0.f;
#pragma unroll
        for (int kk = 0; kk < 32; ++kk) {
            float4 xa = XA4[l][kk];           // broadcast
            float4 xt = XT4[kk][lane];        // conflict-free b128
            s = fmaf(xa.x, xt.x, s);
            s = fmaf(xa.y, xt.y, s);
            s = fmaf(xa.z, xt.z, s);
            s = fmaf(xa.w, xt.w, s);
        }
        s *= scale;
        float sval = (lane < LL) ? s : -INFINITY;
        float mx = sval;
#pragma unroll
        for (int off = 32; off; off >>= 1) mx = fmaxf(mx, __shfl_xor(mx, off));
        float e = (lane < LL) ? __expf(sval - mx) : 0.f;
        float sum = e, pa = e * pvs[lane], qa = e * qvs[lane];
#pragma unroll
        for (int off = 32; off; off >>= 1) {
            sum += __shfl_xor(sum, off);
            pa  += __shfl_xor(pa, off);
            qa  += __shfl_xor(qa, off);
        }
        float inv = 1.f / sum;
        local += (pa * inv + ab) * (qa * inv);
    }
    if (lane == 0) partial[w] = local;
    __syncthreads();
    if (t == 0) {
        float s = partial[0] + partial[1] + partial[2] + partial[3];
        out[b] = 1.f / (1.f + expf(-(s + fc_b[0])));
    }
}

// ---------------------------------------------------------------------------
extern "C" void kernel_launch(void* const* d_in, const int* in_sizes, int n_in,
                              void* d_out, int out_size, void* d_ws, size_t ws_size,
                              hipStream_t stream) {
    const float* emb     = (const float*)d_in[0];
    const float* bases   = (const float*)d_in[1];
    const float* comp    = (const float*)d_in[2];
    const float* root_w  = (const float*)d_in[3];
    const float* root_b  = (const float*)d_in[4];
    const float* wq      = (const float*)d_in[5];
    const float* wk      = (const float*)d_in[6];
    const float* wv      = (const float*)d_in[7];
    const float* attn_w  = (const float*)d_in[8];
    const float* attn_b  = (const float*)d_in[9];
    const float* fc_w    = (const float*)d_in[10];
    const float* fc_b    = (const float*)d_in[11];
    const int* node_ids  = (const int*)d_in[12];
    const int* edge_index= (const int*)d_in[13];
    const int* edge_type = (const int*)d_in[14];
    const int* sent_ids  = (const int*)d_in[15];
    float* out = (float*)d_out;

    float* ws = (float*)d_ws;
    float* Wcat = ws;                         // 98304
    float* A    = ws + 98304;                 // 16384
    float* va   = ws + 114688;                // 128
    float* vf   = ws + 114816;                // 128
    float* pv   = ws + 114944;                // 3200
    float* qv   = ws + 118144;                // 3200
    float* Xws  = ws + 121344;                // 409600
    float* XAws = ws + 530944;                // 409600
    int* rep     = (int*)(ws + 940544);       // 3200
    int* segoff  = (int*)(ws + 943744);       // 64*251 = 16064
    int* recbuf2 = (int*)(ws + 959808);       // 65536
    // total ~1.03M elems ≈ 4.1 MiB

    hipLaunchKernelGGL(precompute_all, dim3(513), dim3(256), 0, stream,
                       bases, comp, root_w, wq, wk, wv, attn_w, fc_w,
                       Wcat, A, va, vf);
    hipLaunchKernelGGL(matchseg, dim3(BDIM), dim3(512), 0, stream,
                       edge_index, edge_type, sent_ids, rep, segoff, recbuf2);
    hipLaunchKernelGGL(gemm_fused, dim3(BDIM * LL / GROWS), dim3(512), 0, stream,
                       emb, Wcat, A, root_b, va, vf, node_ids, sent_ids,
                       rep, segoff, recbuf2, Xws, XAws, pv, qv);
    hipLaunchKernelGGL(attn_batch, dim3(BDIM), dim3(256), 0, stream,
                       Xws, XAws, pv, qv, attn_b, fc_b, out);
}

// Round 8
// 191.759 us; speedup vs baseline: 1.3134x; 1.3134x over previous
//
#include <hip/hip_runtime.h>
#include <math.h>

#define BDIM 64
#define NN   2048
#define EE   8192
#define LL   50
#define DD   128
#define RR   5
#define NBASES 4
#define H3   192
#define RECCAP 1024
#define KDIM 768          // 128 (root) + 5*128 (relations)
#define MT   16           // rows per gemm block
#define KC   64           // K-chunk staged in LDS

__device__ __forceinline__ void fma4(float4& a, float s, const float4& w) {
    a.x = fmaf(s, w.x, a.x); a.y = fmaf(s, w.y, a.y);
    a.z = fmaf(s, w.z, a.z); a.w = fmaf(s, w.w, a.w);
}

// ---------------------------------------------------------------------------
// K1: all small precomputes in one launch.
//   blocks [0,384):   Wcat[768][128] = [root_w ; W_r = comp.bases]
//   blocks [384,512): A[i][j] = wq[i]·wk[j]
//   block  512:       va/vf = wv·attn_w / wv·fc_w
// ---------------------------------------------------------------------------
__global__ __launch_bounds__(256) void precompute_all(
        const float* __restrict__ bases, const float* __restrict__ comp,
        const float* __restrict__ root_w, const float* __restrict__ wq,
        const float* __restrict__ wk, const float* __restrict__ wv,
        const float* __restrict__ attn_w, const float* __restrict__ fc_w,
        float* __restrict__ Wcat, float* __restrict__ A,
        float* __restrict__ va, float* __restrict__ vf) {
    int blk = blockIdx.x, t = threadIdx.x;
    if (blk < 384) {
        int idx = blk * 256 + t;              // < 98304 = 768*128
        int k = idx >> 7, o = idx & 127;
        if (k < DD) {
            Wcat[idx] = root_w[idx];
        } else {
            int r = (k - DD) >> 7, i = (k - DD) & 127;
            float s = 0.f;
#pragma unroll
            for (int bb = 0; bb < NBASES; ++bb)
                s += comp[r * NBASES + bb] * bases[bb * DD * DD + i * DD + o];
            Wcat[idx] = s;
        }
    } else if (blk < 512) {
        int i = blk - 384;
        __shared__ float wqs[H3];
        if (t < H3) wqs[t] = wq[i * H3 + t];
        __syncthreads();
        if (t < DD) {
            const float4* wkr = (const float4*)(wk + t * H3);
            float s = 0.f;
#pragma unroll
            for (int d4 = 0; d4 < H3 / 4; ++d4) {
                float4 v = wkr[d4];
                s += wqs[4*d4]*v.x + wqs[4*d4+1]*v.y + wqs[4*d4+2]*v.z + wqs[4*d4+3]*v.w;
            }
            A[i * DD + t] = s;
        }
    } else {
        if (t < DD) {
            const float4* wr = (const float4*)(wv + t * H3);
            float a = 0.f, f = 0.f;
#pragma unroll
            for (int d4 = 0; d4 < H3 / 4; ++d4) {
                float4 v = wr[d4];
                a += v.x*attn_w[4*d4] + v.y*attn_w[4*d4+1] + v.z*attn_w[4*d4+2] + v.w*attn_w[4*d4+3];
                f += v.x*fc_w[4*d4] + v.y*fc_w[4*d4+1] + v.z*fc_w[4*d4+2] + v.w*fc_w[4*d4+3];
            }
            va[t] = a; vf[t] = f;
        }
    }
}

// ---------------------------------------------------------------------------
// K2: matchseg — one block per batch. Scan edges once, bucket matches by
// (l,r) with an LDS prefix sum -> segmented recbuf2 + segoff[b][251].
// ---------------------------------------------------------------------------
__global__ __launch_bounds__(512) void matchseg(const int* __restrict__ edge_index,
                                                const int* __restrict__ edge_type,
                                                const int* __restrict__ sent_ids,
                                                int* __restrict__ rep,
                                                int* __restrict__ segoff,
                                                int* __restrict__ recbuf2) {
    int b = blockIdx.x, t = threadIdx.x;
    __shared__ int mark[NN];
    __shared__ int scnt[LL * RR];
    __shared__ int soff[LL * RR + 1];
    __shared__ int scan[256];
    __shared__ int recs[RECCAP];
    __shared__ int lcnt;

    for (int i = t; i < NN; i += 512) mark[i] = -1;
    if (t < LL * RR) scnt[t] = 0;
    if (t == 0) lcnt = 0;
    __syncthreads();
    const int* sb = sent_ids + b * LL;
    if (t < LL) mark[sb[t]] = t;            // duplicates: arbitrary but consistent winner
    __syncthreads();
    if (t < LL) rep[b * LL + t] = mark[sb[t]];

    const int* src_arr = edge_index + (size_t)b * 2 * EE;
    const int* tgt_arr = src_arr + EE;
    const int* et_arr  = edge_type + (size_t)b * EE;
    const int4* tgt4 = (const int4*)tgt_arr;
    for (int i4 = t; i4 < EE / 4; i4 += 512) {
        int4 v = tgt4[i4];
        int e0 = 4 * i4;
        int lv[4] = {mark[v.x], mark[v.y], mark[v.z], mark[v.w]};
#pragma unroll
        for (int k = 0; k < 4; ++k) {
            int l = lv[k];
            if (l >= 0) {
                int e = e0 + k;
                int r = et_arr[e];
                int s = src_arr[e];
                int pos = atomicAdd(&lcnt, 1);
                if (pos < RECCAP) {
                    recs[pos] = (l << 14) | (r << 11) | s;
                    atomicAdd(&scnt[l * RR + r], 1);
                }
            }
        }
    }
    __syncthreads();
    // inclusive scan of scnt[0..249] over 256 lanes (Hillis-Steele)
    if (t < 256) scan[t] = (t < LL * RR) ? scnt[t] : 0;
    __syncthreads();
    for (int off = 1; off < 256; off <<= 1) {
        int v = 0;
        if (t < 256 && t >= off) v = scan[t - off];
        __syncthreads();
        if (t < 256) scan[t] += v;
        __syncthreads();
    }
    if (t == 0) soff[0] = 0;
    if (t < LL * RR) soff[t + 1] = scan[t];
    if (t < LL * RR) scnt[t] = 0;           // reset cursors
    __syncthreads();
    if (t <= LL * RR) segoff[b * (LL * RR + 1) + t] = soff[t];
    int nm = (lcnt < RECCAP) ? lcnt : RECCAP;
    for (int i = t; i < nm; i += 512) {
        int rc = recs[i];
        int key = (rc >> 14) * RR + ((rc >> 11) & 7);
        int pos = soff[key] + atomicAdd(&scnt[key], 1);
        recbuf2[b * RECCAP + pos] = rc;
    }
}

// ---------------------------------------------------------------------------
// K3: aggregate — one wave per (b,l). Gather xnode + per-relation mean sums
// from the segmented record list, write U row [xnode | xsum_r / c_r] (K=768).
// ---------------------------------------------------------------------------
__global__ __launch_bounds__(64) void aggregate(const float* __restrict__ emb,
                                                const int* __restrict__ node_ids,
                                                const int* __restrict__ sent_ids,
                                                const int* __restrict__ rep,
                                                const int* __restrict__ segoff,
                                                const int* __restrict__ recbuf2,
                                                float* __restrict__ U) {
    int bl = blockIdx.x;
    int b  = bl / LL;
    int lane = threadIdx.x;
    const int* nid = node_ids + (size_t)b * NN;
    int myrep = rep[bl];
    const int* so = segoff + b * (LL * RR + 1) + myrep * RR;
    const int* rb = recbuf2 + b * RECCAP;
    float* Urow = U + (size_t)bl * KDIM;

    int row = nid[sent_ids[bl]];
    Urow[lane]      = emb[(size_t)row * DD + lane];
    Urow[lane + 64] = emb[(size_t)row * DD + 64 + lane];

#pragma unroll
    for (int r = 0; r < RR; ++r) {
        int s0 = so[r], s1 = so[r + 1];
        float a0 = 0.f, a1 = 0.f;
        for (int j = s0; j < s1; ++j) {
            int s = rb[j] & 2047;
            int rw = nid[s];
            a0 += emb[(size_t)rw * DD + lane];
            a1 += emb[(size_t)rw * DD + 64 + lane];
        }
        float inv = (s1 > s0) ? 1.f / (float)(s1 - s0) : 0.f;
        Urow[DD + r * DD + lane]      = a0 * inv;
        Urow[DD + r * DD + 64 + lane] = a1 * inv;
    }
}

// ---------------------------------------------------------------------------
// K4: gemm_tiled — 200 blocks x 256 threads, 16 rows x 128 cols per block.
// U tile LDS-staged once; Wcat streamed through a [KC][128] LDS chunk buffer
// (12 chunks), amortized over 16 rows. Thread = 2 rows x 4 cols register tile.
// Then XA = X@A reusing the chunk buffer (2 chunks), and p/q wave reductions.
// ---------------------------------------------------------------------------
__global__ __launch_bounds__(256) void gemm_tiled(const float* __restrict__ U,
                                                  const float* __restrict__ Wcat,
                                                  const float* __restrict__ A,
                                                  const float* __restrict__ root_b,
                                                  const float* __restrict__ va,
                                                  const float* __restrict__ vf,
                                                  float* __restrict__ Xws,
                                                  float* __restrict__ XAws,
                                                  float* __restrict__ pv,
                                                  float* __restrict__ qv) {
    __shared__ float Us[MT][KDIM];     // 48 KB
    __shared__ float Wb[KC][DD];       // 32 KB
    __shared__ float Xs[MT][DD];       // 8 KB
    __shared__ float vas[DD], vfs[DD];

    int t = threadIdx.x;
    int row0 = blockIdx.x * MT;
    int cg = t & 31;                   // col group: cols 4cg..4cg+3
    int rg = t >> 5;                   // 0..7 -> rows 2rg, 2rg+1
    int r0 = 2 * rg, r1 = r0 + 1;

    // stage U tile (coalesced float4)
    const float4* Ug = (const float4*)(U + (size_t)row0 * KDIM);
    for (int i = t; i < MT * KDIM / 4; i += 256) ((float4*)Us)[i] = Ug[i];
    if (t < DD) { vas[t] = va[t]; vfs[t] = vf[t]; }

    // --- X = U @ Wcat + root_b
    float4 rbias = *(const float4*)(root_b + 4 * cg);
    float4 acc0 = rbias, acc1 = rbias;
    for (int c = 0; c < KDIM / KC; ++c) {
        __syncthreads();               // Us ready (c=0) / Wb consumed (c>0)
        const float4* Wg = (const float4*)(Wcat + (size_t)c * KC * DD);
        for (int i = t; i < KC * DD / 4; i += 256) ((float4*)Wb)[i] = Wg[i];
        __syncthreads();
        const float* u0r = Us[r0] + c * KC;
        const float* u1r = Us[r1] + c * KC;
#pragma unroll 8
        for (int kc = 0; kc < KC; ++kc) {
            float u0 = u0r[kc], u1 = u1r[kc];
            float4 w = ((const float4*)Wb[kc])[cg];
            fma4(acc0, u0, w); fma4(acc1, u1, w);
        }
    }
    *(float4*)&Xs[r0][4 * cg] = acc0;
    *(float4*)&Xs[r1][4 * cg] = acc1;
    *(float4*)(Xws + (size_t)(row0 + r0) * DD + 4 * cg) = acc0;
    *(float4*)(Xws + (size_t)(row0 + r1) * DD + 4 * cg) = acc1;

    // --- XA = X @ A (2 chunks of A through Wb)
    float4 z0 = {0,0,0,0}, z1 = {0,0,0,0};
    for (int c = 0; c < DD / KC; ++c) {
        __syncthreads();               // Wb consumed; also orders Xs writes before reads
        const float4* Ag = (const float4*)(A + (size_t)c * KC * DD);
        for (int i = t; i < KC * DD / 4; i += 256) ((float4*)Wb)[i] = Ag[i];
        __syncthreads();
        const float* x0r = Xs[r0] + c * KC;
        const float* x1r = Xs[r1] + c * KC;
#pragma unroll 8
        for (int kc = 0; kc < KC; ++kc) {
            float x0 = x0r[kc], x1 = x1r[kc];
            float4 a = ((const float4*)Wb[kc])[cg];
            fma4(z0, x0, a); fma4(z1, x1, a);
        }
    }
    *(float4*)(XAws + (size_t)(row0 + r0) * DD + 4 * cg) = z0;
    *(float4*)(XAws + (size_t)(row0 + r1) * DD + 4 * cg) = z1;
    __syncthreads();

    // --- p/q: wave w handles rows 4w..4w+3
    int lane = t & 63, w = t >> 6;
#pragma unroll
    for (int rr = 0; rr < 4; ++rr) {
        int m = 4 * w + rr;
        float xv0 = Xs[m][lane], xv1 = Xs[m][lane + 64];
        float pp = xv0 * vas[lane] + xv1 * vas[lane + 64];
        float qq = xv0 * vfs[lane] + xv1 * vfs[lane + 64];
#pragma unroll
        for (int off = 32; off; off >>= 1) {
            pp += __shfl_xor(pp, off);
            qq += __shfl_xor(qq, off);
        }
        if (lane == 0) { pv[row0 + m] = pp; qv[row0 + m] = qq; }
    }
}

// ---------------------------------------------------------------------------
// K5: attn_batch — one block (4 waves) per batch. X staged transposed as
// float4 (XT4[k][m]), lane m owns score column m. Wave w handles rows
// l = w, w+4, ... Softmax + pooled product in-wave; out[b] written directly.
// ---------------------------------------------------------------------------
__global__ __launch_bounds__(256) void attn_batch(const float* __restrict__ Xws,
                                                  const float* __restrict__ XAws,
                                                  const float* __restrict__ pv,
                                                  const float* __restrict__ qv,
                                                  const float* __restrict__ attn_b,
                                                  const float* __restrict__ fc_b,
                                                  float* __restrict__ out) {
    __shared__ float4 XT4[32][64];    // XT4[k][m] = X[m][4k..4k+3]; 32 KB
    __shared__ float4 XA4[LL][32];    // XA rows as float4; 25.6 KB
    __shared__ float pvs[64], qvs[64];
    __shared__ float partial[4];

    int b = blockIdx.x, t = threadIdx.x;
    int w = t >> 6, lane = t & 63;

    const float4* Xb4  = (const float4*)(Xws  + (size_t)b * LL * DD);
    const float4* XAb4 = (const float4*)(XAws + (size_t)b * LL * DD);
    for (int idx = t; idx < LL * 32; idx += 256) {
        int m = idx >> 5, k = idx & 31;
        XT4[k][m] = Xb4[idx];                 // coalesced read, scattered LDS write
        ((float4*)XA4)[idx] = XAb4[idx];
    }
    if (t < 64) {
        pvs[t] = (t < LL) ? pv[b * LL + t] : 0.f;
        qvs[t] = (t < LL) ? qv[b * LL + t] : 0.f;
    }
    __syncthreads();

    const float scale = 0.07216878364870322f;  // 1/sqrt(192)
    float ab = attn_b[0];
    float local = 0.f;
    for (int l = w; l < LL; l += 4) {
        float s = 0.f;
#pragma unroll
        for (int kk = 0; kk < 32; ++kk) {
            float4 xa = XA4[l][kk];           // broadcast
            float4 xt = XT4[kk][lane];        // conflict-free b128
            s = fmaf(xa.x, xt.x, s);
            s = fmaf(xa.y, xt.y, s);
            s = fmaf(xa.z, xt.z, s);
            s = fmaf(xa.w, xt.w, s);
        }
        s *= scale;
        float sval = (lane < LL) ? s : -INFINITY;
        float mx = sval;
#pragma unroll
        for (int off = 32; off; off >>= 1) mx = fmaxf(mx, __shfl_xor(mx, off));
        float e = (lane < LL) ? __expf(sval - mx) : 0.f;
        float sum = e, pa = e * pvs[lane], qa = e * qvs[lane];
#pragma unroll
        for (int off = 32; off; off >>= 1) {
            sum += __shfl_xor(sum, off);
            pa  += __shfl_xor(pa, off);
            qa  += __shfl_xor(qa, off);
        }
        float inv = 1.f / sum;
        local += (pa * inv + ab) * (qa * inv);
    }
    if (lane == 0) partial[w] = local;
    __syncthreads();
    if (t == 0) {
        float s = partial[0] + partial[1] + partial[2] + partial[3];
        out[b] = 1.f / (1.f + expf(-(s + fc_b[0])));
    }
}

// ---------------------------------------------------------------------------
extern "C" void kernel_launch(void* const* d_in, const int* in_sizes, int n_in,
                              void* d_out, int out_size, void* d_ws, size_t ws_size,
                              hipStream_t stream) {
    const float* emb     = (const float*)d_in[0];
    const float* bases   = (const float*)d_in[1];
    const float* comp    = (const float*)d_in[2];
    const float* root_w  = (const float*)d_in[3];
    const float* root_b  = (const float*)d_in[4];
    const float* wq      = (const float*)d_in[5];
    const float* wk      = (const float*)d_in[6];
    const float* wv      = (const float*)d_in[7];
    const float* attn_w  = (const float*)d_in[8];
    const float* attn_b  = (const float*)d_in[9];
    const float* fc_w    = (const float*)d_in[10];
    const float* fc_b    = (const float*)d_in[11];
    const int* node_ids  = (const int*)d_in[12];
    const int* edge_index= (const int*)d_in[13];
    const int* edge_type = (const int*)d_in[14];
    const int* sent_ids  = (const int*)d_in[15];
    float* out = (float*)d_out;

    float* ws = (float*)d_ws;
    float* Wcat = ws;                         // 98304
    float* A    = ws + 98304;                 // 16384
    float* va   = ws + 114688;                // 128
    float* vf   = ws + 114816;                // 128
    float* pv   = ws + 114944;                // 3200
    float* qv   = ws + 118144;                // 3200
    float* Xws  = ws + 121344;                // 409600
    float* XAws = ws + 530944;                // 409600
    float* U    = ws + 940544;                // 3200*768 = 2457600
    int* rep     = (int*)(ws + 3398144);      // 3200
    int* segoff  = (int*)(ws + 3401344);      // 64*251 = 16064
    int* recbuf2 = (int*)(ws + 3417408);      // 65536
    // total ~3.48M elems ≈ 13.3 MiB

    hipLaunchKernelGGL(precompute_all, dim3(513), dim3(256), 0, stream,
                       bases, comp, root_w, wq, wk, wv, attn_w, fc_w,
                       Wcat, A, va, vf);
    hipLaunchKernelGGL(matchseg, dim3(BDIM), dim3(512), 0, stream,
                       edge_index, edge_type, sent_ids, rep, segoff, recbuf2);
    hipLaunchKernelGGL(aggregate, dim3(BDIM * LL), dim3(64), 0, stream,
                       emb, node_ids, sent_ids, rep, segoff, recbuf2, U);
    hipLaunchKernelGGL(gemm_tiled, dim3(BDIM * LL / MT), dim3(256), 0, stream,
                       U, Wcat, A, root_b, va, vf, Xws, XAws, pv, qv);
    hipLaunchKernelGGL(attn_batch, dim3(BDIM), dim3(256), 0, stream,
                       Xws, XAws, pv, qv, attn_b, fc_b, out);
}